// Round 6
// baseline (326.483 us; speedup 1.0000x reference)
//
#include <hip/hip_runtime.h>
#include <cstdint>
#include <cstddef>

// ---------------------------------------------------------------------------
// GCN 4-layer + residual + FC on MI355X, round 6.
// - Bucketed CSR build (round 4), memsets replaced by init_kernel.
// - Layer-1 GEMM fused with residual GEMM (x read once, dual accumulators).
// - agg_kernel: node-PAIR per wave -> 4 gather loads in flight.
// - H, O, R all bf16 (fp32 accumulation everywhere).
// ---------------------------------------------------------------------------

#define SLOTS 64
#define BCAP 5120          // max edges per 256-node bucket (mean 4096, +16 sigma)
#define ACHUNK 4096        // edges per block in pass A

__device__ __forceinline__ unsigned short f2bf(float f) {
  union { float f; unsigned u; } v; v.f = f;
  unsigned r = (v.u + 0x7fffu + ((v.u >> 16) & 1u)) >> 16;
  return (unsigned short)r;
}
__device__ __forceinline__ float bf2f(unsigned short h) {
  union { unsigned u; float f; } v; v.u = ((unsigned)h) << 16;
  return v.f;
}
__device__ __forceinline__ void bf2x2(unsigned u, float* lo, float* hi) {
  union { unsigned x; float f; } a, b;
  a.x = u << 16; b.x = u & 0xFFFF0000u;
  *lo = a.f; *hi = b.f;
}

__global__ void init_kernel(int* __restrict__ gcur_d, int* __restrict__ gcur_s, int nbuck) {
  int i = blockIdx.x * blockDim.x + threadIdx.x;
  if (i < nbuck) { gcur_d[i] = 0; gcur_s[i] = 0; }
}

// ---------------------------------------------------------------------------
// Pass A: bucket edges by dst>>8 (payload dstlow|src) and by src>>8 (payload
// srclow byte). Per-block LDS histogram -> one global atomic per
// (block,bucket) -> contiguous run scatter.
// ---------------------------------------------------------------------------
__global__ __launch_bounds__(256) void bucket_kernel(
    const int* __restrict__ src, const int* __restrict__ dst,
    int* __restrict__ gcur_d, int* __restrict__ gcur_s,
    unsigned* __restrict__ dbuck, unsigned char* __restrict__ sbuck,
    int E, int nbuck) {
  __shared__ int s_src[ACHUNK];
  __shared__ int s_dst[ACHUNK];
  __shared__ int run_d[512];
  __shared__ int run_s[512];
  const int t = threadIdx.x;
  const int base = blockIdx.x * ACHUNK;
  int cnt = E - base;
  if (cnt > ACHUNK) cnt = ACHUNK;

  for (int i = t; i < cnt; i += 256) {
    s_src[i] = src[base + i];
    s_dst[i] = dst[base + i];
  }
  for (int i = t; i < nbuck; i += 256) { run_d[i] = 0; run_s[i] = 0; }
  __syncthreads();
  for (int i = t; i < cnt; i += 256) {
    atomicAdd(&run_d[s_dst[i] >> 8], 1);
    atomicAdd(&run_s[s_src[i] >> 8], 1);
  }
  __syncthreads();
  // Reserve global runs. UNIFORM trip count so barriers are non-divergent.
  {
    const int iters = (nbuck + 255) >> 8;
    for (int it = 0; it < iters; ++it) {
      int i = it * 256 + t;
      int hd = 0, hs = 0;
      if (i < nbuck) { hd = run_d[i]; hs = run_s[i]; }
      __syncthreads();
      if (i < nbuck) {
        run_d[i] = hd ? atomicAdd(&gcur_d[i], hd) : 0;
        run_s[i] = hs ? atomicAdd(&gcur_s[i], hs) : 0;
      }
      __syncthreads();
    }
  }
  for (int i = t; i < cnt; i += 256) {
    int d = s_dst[i], s = s_src[i];
    int bd = d >> 8;
    int pd = atomicAdd(&run_d[bd], 1);
    if (pd < BCAP) dbuck[(size_t)bd * BCAP + pd] = ((unsigned)(d & 255) << 24) | (unsigned)s;
    int bs = s >> 8;
    int ps = atomicAdd(&run_s[bs], 1);
    if (ps < BCAP) sbuck[(size_t)bs * BCAP + ps] = (unsigned char)(s & 255);
  }
}

// ---------------------------------------------------------------------------
// Pass B: one block per dst-bucket. LDS cursors assign padded slots; emit
// deg_in (cnt_arr) and dnorm.
// ---------------------------------------------------------------------------
__global__ __launch_bounds__(256) void csr_kernel(
    const unsigned* __restrict__ dbuck, const int* __restrict__ gcur_d,
    int* __restrict__ col, int* __restrict__ cnt_arr,
    float* __restrict__ dnorm, int N) {
  __shared__ int cur[256];
  const int b = blockIdx.x;
  const int t = threadIdx.x;
  const int node0 = b << 8;
  cur[t] = 0;
  __syncthreads();
  int cnt = gcur_d[b];
  if (cnt > BCAP) cnt = BCAP;
  const unsigned* p = dbuck + (size_t)b * BCAP;
  for (int i = t; i < cnt; i += 256) {
    unsigned e = p[i];
    int nl = e >> 24;
    int s = (int)(e & 0x00FFFFFFu);
    int pos = atomicAdd(&cur[nl], 1);
    if (pos < SLOTS) col[(size_t)(node0 + nl) * SLOTS + pos] = s;
  }
  __syncthreads();
  int node = node0 + t;
  if (node < N) {
    int c = cur[t];
    cnt_arr[node] = c;
    float d = (float)(c < 1 ? 1 : c);
    dnorm[node] = rsqrtf(d);
  }
}

// ---------------------------------------------------------------------------
// Pass C: one block per src-bucket -> deg_out histogram -> snorm.
// ---------------------------------------------------------------------------
__global__ __launch_bounds__(256) void degout_kernel(
    const unsigned char* __restrict__ sbuck, const int* __restrict__ gcur_s,
    float* __restrict__ snorm, int N) {
  __shared__ int cur[256];
  const int b = blockIdx.x;
  const int t = threadIdx.x;
  cur[t] = 0;
  __syncthreads();
  int cnt = gcur_s[b];
  if (cnt > BCAP) cnt = BCAP;
  const unsigned char* p = sbuck + (size_t)b * BCAP;
  for (int i = t; i < cnt; i += 256) atomicAdd(&cur[p[i]], 1);
  __syncthreads();
  int node = (b << 8) + t;
  if (node < N) {
    int c = cur[t];
    snorm[node] = rsqrtf((float)(c < 1 ? 1 : c));
  }
}

// ---------------------------------------------------------------------------
// GEMM tiles: 64 nodes x 64 features per block, 4x4 register tile per thread.
// ---------------------------------------------------------------------------
#define GEMM_STEP(ACC, r, aval, wv)                 \
  ACC[r][0] = fmaf((aval), (wv).x, ACC[r][0]);      \
  ACC[r][1] = fmaf((aval), (wv).y, ACC[r][1]);      \
  ACC[r][2] = fmaf((aval), (wv).z, ACC[r][2]);      \
  ACC[r][3] = fmaf((aval), (wv).w, ACC[r][3]);

#define GEMM_ROW(ACC, W_LDS, kc)                                         \
  { float4 w0 = *(const float4*)&W_LDS[kc + 0][tx4];                     \
    float4 w1 = *(const float4*)&W_LDS[kc + 1][tx4];                     \
    float4 w2 = *(const float4*)&W_LDS[kc + 2][tx4];                     \
    float4 w3 = *(const float4*)&W_LDS[kc + 3][tx4];                     \
    GEMM_STEP(ACC, 0, a0.x, w0) GEMM_STEP(ACC, 0, a0.y, w1) GEMM_STEP(ACC, 0, a0.z, w2) GEMM_STEP(ACC, 0, a0.w, w3) \
    GEMM_STEP(ACC, 1, a1.x, w0) GEMM_STEP(ACC, 1, a1.y, w1) GEMM_STEP(ACC, 1, a1.z, w2) GEMM_STEP(ACC, 1, a1.w, w3) \
    GEMM_STEP(ACC, 2, a2.x, w0) GEMM_STEP(ACC, 2, a2.y, w1) GEMM_STEP(ACC, 2, a2.z, w2) GEMM_STEP(ACC, 2, a2.w, w3) \
    GEMM_STEP(ACC, 3, a3.x, w0) GEMM_STEP(ACC, 3, a3.y, w1) GEMM_STEP(ACC, 3, a3.z, w2) GEMM_STEP(ACC, 3, a3.w, w3) }

#define STAGE_W_TILE(W_PTR, W_LDS)                                \
  { const float* s_ = (W_PTR) + (size_t)srow * 64 + scol;         \
    float4 q0 = *(const float4*)(s_ + 0);                         \
    float4 q1 = *(const float4*)(s_ + 4);                         \
    float4 q2 = *(const float4*)(s_ + 8);                         \
    float4 q3 = *(const float4*)(s_ + 12);                        \
    *(float4*)&W_LDS[srow][scol + 0]  = q0;                       \
    *(float4*)&W_LDS[srow][scol + 4]  = q1;                       \
    *(float4*)&W_LDS[srow][scol + 8]  = q2;                       \
    *(float4*)&W_LDS[srow][scol + 12] = q3; }

// ---------------------------------------------------------------------------
// Layer-1 fused GEMM: reads x once, computes
//   H = (x @ W1) * snorm  (bf16)   and   R = x @ Wres + bres  (bf16)
// ---------------------------------------------------------------------------
__global__ __launch_bounds__(256) void gemm1_kernel(
    const float* __restrict__ X, const float* __restrict__ W1,
    const float* __restrict__ Wres, const float* __restrict__ bres,
    const float* __restrict__ norm,
    unsigned short* __restrict__ Hout, unsigned short* __restrict__ Rout, int n) {
  __shared__ float in_lds[64][68];
  __shared__ float w_lds[64][64];
  __shared__ float wr_lds[64][64];
  const int t = threadIdx.x;
  const int tx4 = (t & 15) * 4;
  const int ty4 = (t >> 4) * 4;
  const int node0 = blockIdx.x * 64;
  const int srow = t >> 2;
  const int scol = (t & 3) * 16;

  float acc[4][4], acc2[4][4];
#pragma unroll
  for (int r = 0; r < 4; r++)
#pragma unroll
    for (int j = 0; j < 4; j++) { acc[r][j] = 0.f; acc2[r][j] = 0.f; }

  for (int kb = 0; kb < 128; kb += 64) {
    {
      int gi = node0 + srow;
      float4 v0, v1, v2, v3;
      if (gi < n) {
        const float* s = X + (size_t)gi * 128 + kb + scol;
        v0 = *(const float4*)(s + 0);
        v1 = *(const float4*)(s + 4);
        v2 = *(const float4*)(s + 8);
        v3 = *(const float4*)(s + 12);
      } else {
        v0 = v1 = v2 = v3 = make_float4(0.f, 0.f, 0.f, 0.f);
      }
      *(float4*)&in_lds[srow][scol + 0]  = v0;
      *(float4*)&in_lds[srow][scol + 4]  = v1;
      *(float4*)&in_lds[srow][scol + 8]  = v2;
      *(float4*)&in_lds[srow][scol + 12] = v3;
    }
    STAGE_W_TILE(W1 + (size_t)kb * 64, w_lds)
    STAGE_W_TILE(Wres + (size_t)kb * 64, wr_lds)
    __syncthreads();

    for (int kc = 0; kc < 64; kc += 4) {
      float4 a0 = *(const float4*)&in_lds[ty4 + 0][kc];
      float4 a1 = *(const float4*)&in_lds[ty4 + 1][kc];
      float4 a2 = *(const float4*)&in_lds[ty4 + 2][kc];
      float4 a3 = *(const float4*)&in_lds[ty4 + 3][kc];
      GEMM_ROW(acc, w_lds, kc)
      GEMM_ROW(acc2, wr_lds, kc)
    }
    __syncthreads();
  }

#pragma unroll
  for (int r = 0; r < 4; r++) {
    int gi = node0 + ty4 + r;
    if (gi >= n) continue;
    float s = norm[gi];
    ushort4 h;
    h.x = f2bf(acc[r][0] * s);
    h.y = f2bf(acc[r][1] * s);
    h.z = f2bf(acc[r][2] * s);
    h.w = f2bf(acc[r][3] * s);
    *(ushort4*)&Hout[(size_t)gi * 64 + tx4] = h;
    ushort4 rr;
    rr.x = f2bf(acc2[r][0] + bres[tx4 + 0]);
    rr.y = f2bf(acc2[r][1] + bres[tx4 + 1]);
    rr.z = f2bf(acc2[r][2] + bres[tx4 + 2]);
    rr.w = f2bf(acc2[r][3] + bres[tx4 + 3]);
    *(ushort4*)&Rout[(size_t)gi * 64 + tx4] = rr;
  }
}

// bf16 input [n][64]; out bf16 = (X@W)*snorm
__global__ __launch_bounds__(256) void gemm_bf16_kernel(
    const unsigned short* __restrict__ X, const float* __restrict__ W,
    const float* __restrict__ norm, unsigned short* __restrict__ out, int n) {
  __shared__ float in_lds[64][68];
  __shared__ float w_lds[64][64];
  const int t = threadIdx.x;
  const int tx4 = (t & 15) * 4;
  const int ty4 = (t >> 4) * 4;
  const int node0 = blockIdx.x * 64;
  const int srow = t >> 2;
  const int scol = (t & 3) * 16;

  float acc[4][4];
#pragma unroll
  for (int r = 0; r < 4; r++)
#pragma unroll
    for (int j = 0; j < 4; j++) acc[r][j] = 0.f;

  {
    int gi = node0 + srow;
    float f[16];
    if (gi < n) {
      const unsigned short* s = X + (size_t)gi * 64 + scol;
      uint4 u0 = *(const uint4*)(s + 0);
      uint4 u1 = *(const uint4*)(s + 8);
      bf2x2(u0.x, &f[0], &f[1]);   bf2x2(u0.y, &f[2], &f[3]);
      bf2x2(u0.z, &f[4], &f[5]);   bf2x2(u0.w, &f[6], &f[7]);
      bf2x2(u1.x, &f[8], &f[9]);   bf2x2(u1.y, &f[10], &f[11]);
      bf2x2(u1.z, &f[12], &f[13]); bf2x2(u1.w, &f[14], &f[15]);
    } else {
#pragma unroll
      for (int j = 0; j < 16; j++) f[j] = 0.f;
    }
#pragma unroll
    for (int j = 0; j < 16; j += 4)
      *(float4*)&in_lds[srow][scol + j] = make_float4(f[j], f[j+1], f[j+2], f[j+3]);
  }
  STAGE_W_TILE(W, w_lds)
  __syncthreads();

  for (int kc = 0; kc < 64; kc += 4) {
    float4 a0 = *(const float4*)&in_lds[ty4 + 0][kc];
    float4 a1 = *(const float4*)&in_lds[ty4 + 1][kc];
    float4 a2 = *(const float4*)&in_lds[ty4 + 2][kc];
    float4 a3 = *(const float4*)&in_lds[ty4 + 3][kc];
    GEMM_ROW(acc, w_lds, kc)
  }

#pragma unroll
  for (int r = 0; r < 4; r++) {
    int gi = node0 + ty4 + r;
    if (gi >= n) continue;
    float s = norm[gi];
    ushort4 o;
    o.x = f2bf(acc[r][0] * s);
    o.y = f2bf(acc[r][1] * s);
    o.z = f2bf(acc[r][2] * s);
    o.w = f2bf(acc[r][3] * s);
    *(ushort4*)&out[(size_t)gi * 64 + tx4] = o;
  }
}

// ---------------------------------------------------------------------------
// Aggregate: node PAIR per wave. lane = (sub, fl): sub = lane>>4 picks edge
// within a 4-edge slot, fl = lane&15 picks a 4-feature quad (uint2 = 4 bf16).
// 2 slots x 2 nodes -> 4 gather loads in flight per iteration.
// ---------------------------------------------------------------------------
#define UNPACK_ADD(u, A)                         \
  { float f0, f1, f2, f3;                        \
    bf2x2((u).x, &f0, &f1);                      \
    bf2x2((u).y, &f2, &f3);                      \
    A[0] += f0; A[1] += f1; A[2] += f2; A[3] += f3; }

template <int RELU>
__global__ __launch_bounds__(256) void agg_kernel(
    const unsigned short* __restrict__ H, const int* __restrict__ cnt_arr,
    const int* __restrict__ col, const float* __restrict__ dnorm,
    const float* __restrict__ bias, unsigned short* __restrict__ O,
    int n) {
  const int lane = threadIdx.x & 63;
  const int sub = lane >> 4;       // 0..3: edge within slot
  const int fl  = lane & 15;       // feature quad
  const int wave = (blockIdx.x * blockDim.x + threadIdx.x) >> 6;
  const int nwaves = (gridDim.x * blockDim.x) >> 6;
  const uint2* __restrict__ H2 = (const uint2*)H;
  const float4 bb = ((const float4*)bias)[fl];

  for (int v0 = wave * 2; v0 < n; v0 += nwaves * 2) {
    const int v1 = v0 + 1;
    int cnt0 = cnt_arr[v0];
    int cnt1 = (v1 < n) ? cnt_arr[v1] : 0;
    if (cnt0 > SLOTS) cnt0 = SLOTS;
    if (cnt1 > SLOTS) cnt1 = SLOTS;
    const size_t base0 = (size_t)v0 * SLOTS;
    const size_t base1 = (size_t)v1 * SLOTS;
    int cv0 = (lane < cnt0) ? col[base0 + lane] : 0;
    int cv1 = (lane < cnt1) ? col[base1 + lane] : 0;
    float a0[4] = {0.f, 0.f, 0.f, 0.f};
    float b0[4] = {0.f, 0.f, 0.f, 0.f};
    float a1[4] = {0.f, 0.f, 0.f, 0.f};
    float b1[4] = {0.f, 0.f, 0.f, 0.f};
    const int cmax = cnt0 > cnt1 ? cnt0 : cnt1;
    for (int j = 0; j < cmax; j += 8) {
      const int e0 = j + sub;
      const int e1 = j + 4 + sub;
      int c00 = __shfl(cv0, e0);
      int c01 = __shfl(cv0, e1);
      int c10 = __shfl(cv1, e0);
      int c11 = __shfl(cv1, e1);
      if (e0 < cnt0) { uint2 u = H2[(size_t)c00 * 16 + fl]; UNPACK_ADD(u, a0) }
      if (e0 < cnt1) { uint2 u = H2[(size_t)c10 * 16 + fl]; UNPACK_ADD(u, a1) }
      if (e1 < cnt0) { uint2 u = H2[(size_t)c01 * 16 + fl]; UNPACK_ADD(u, b0) }
      if (e1 < cnt1) { uint2 u = H2[(size_t)c11 * 16 + fl]; UNPACK_ADD(u, b1) }
    }
    float r0[4], r1[4];
#pragma unroll
    for (int i = 0; i < 4; i++) {
      float s0 = a0[i] + b0[i];
      s0 += __shfl_xor(s0, 16);
      s0 += __shfl_xor(s0, 32);
      r0[i] = s0;
      float s1 = a1[i] + b1[i];
      s1 += __shfl_xor(s1, 16);
      s1 += __shfl_xor(s1, 32);
      r1[i] = s1;
    }
    if (sub == 0) {
      float d = dnorm[v0];
      float q0 = r0[0] * d + bb.x;
      float q1 = r0[1] * d + bb.y;
      float q2 = r0[2] * d + bb.z;
      float q3 = r0[3] * d + bb.w;
      if (RELU) {
        q0 = fmaxf(q0, 0.f); q1 = fmaxf(q1, 0.f);
        q2 = fmaxf(q2, 0.f); q3 = fmaxf(q3, 0.f);
      }
      ushort4 o;
      o.x = f2bf(q0); o.y = f2bf(q1); o.z = f2bf(q2); o.w = f2bf(q3);
      *(ushort4*)&O[base0 + 4 * fl] = o;
    } else if (sub == 1 && v1 < n) {
      float d = dnorm[v1];
      float q0 = r1[0] * d + bb.x;
      float q1 = r1[1] * d + bb.y;
      float q2 = r1[2] * d + bb.z;
      float q3 = r1[3] * d + bb.w;
      if (RELU) {
        q0 = fmaxf(q0, 0.f); q1 = fmaxf(q1, 0.f);
        q2 = fmaxf(q2, 0.f); q3 = fmaxf(q3, 0.f);
      }
      ushort4 o;
      o.x = f2bf(q0); o.y = f2bf(q1); o.z = f2bf(q2); o.w = f2bf(q3);
      *(ushort4*)&O[base1 + 4 * fl] = o;
    }
  }
}

// ---------------------------------------------------------------------------
// Final: out[n][16] = relu(O4 + R) @ Wop + bop  (O4, R bf16)
// ---------------------------------------------------------------------------
__global__ __launch_bounds__(256) void final_kernel(
    const unsigned short* __restrict__ O4, const unsigned short* __restrict__ R,
    const float* __restrict__ Wop, const float* __restrict__ bop,
    float* __restrict__ out, int n) {
  __shared__ float t_lds[64][68];
  __shared__ float wop_lds[64][16];
  const int t = threadIdx.x;
  const int node0 = blockIdx.x * 64;
  const int srow = t >> 2;
  const int scol = (t & 3) * 16;

  ((float4*)&wop_lds[0][0])[t] = ((const float4*)Wop)[t];

  {
    int gi = node0 + srow;
    float f[16];
    if (gi < n) {
      const unsigned short* po = O4 + (size_t)gi * 64 + scol;
      const unsigned short* pr = R + (size_t)gi * 64 + scol;
      uint4 uo0 = *(const uint4*)(po + 0);
      uint4 uo1 = *(const uint4*)(po + 8);
      uint4 ur0 = *(const uint4*)(pr + 0);
      uint4 ur1 = *(const uint4*)(pr + 8);
      float o0, o1, rr0, rr1;
#define ADDRELU2(UO, UR, idx)                         \
      bf2x2(UO, &o0, &o1); bf2x2(UR, &rr0, &rr1);     \
      f[idx] = fmaxf(o0 + rr0, 0.f);                  \
      f[idx + 1] = fmaxf(o1 + rr1, 0.f);
      ADDRELU2(uo0.x, ur0.x, 0)  ADDRELU2(uo0.y, ur0.y, 2)
      ADDRELU2(uo0.z, ur0.z, 4)  ADDRELU2(uo0.w, ur0.w, 6)
      ADDRELU2(uo1.x, ur1.x, 8)  ADDRELU2(uo1.y, ur1.y, 10)
      ADDRELU2(uo1.z, ur1.z, 12) ADDRELU2(uo1.w, ur1.w, 14)
#undef ADDRELU2
    } else {
#pragma unroll
      for (int j = 0; j < 16; j++) f[j] = 0.f;
    }
#pragma unroll
    for (int j = 0; j < 16; j += 4)
      *(float4*)&t_lds[srow][scol + j] = make_float4(f[j], f[j+1], f[j+2], f[j+3]);
  }
  __syncthreads();

  {
    int nn = t >> 2;
    int fg = t & 3;
    float4 a = ((const float4*)bop)[fg];
#pragma unroll 16
    for (int k = 0; k < 64; k++) {
      float tv = t_lds[nn][k];
      float4 w = *(const float4*)&wop_lds[k][fg * 4];
      a.x = fmaf(tv, w.x, a.x);
      a.y = fmaf(tv, w.y, a.y);
      a.z = fmaf(tv, w.z, a.z);
      a.w = fmaf(tv, w.w, a.w);
    }
    int node = node0 + nn;
    if (node < n) *(float4*)&out[(size_t)node * 16 + fg * 4] = a;
  }
}

extern "C" void kernel_launch(void* const* d_in, const int* in_sizes, int n_in,
                              void* d_out, int out_size, void* d_ws, size_t ws_size,
                              hipStream_t stream) {
  const float* x    = (const float*)d_in[0];
  const int*   src  = (const int*)d_in[1];
  const int*   dst  = (const int*)d_in[2];
  const float* W1   = (const float*)d_in[3];
  const float* b1   = (const float*)d_in[4];
  const float* W2   = (const float*)d_in[5];
  const float* b2   = (const float*)d_in[6];
  const float* W3   = (const float*)d_in[7];
  const float* b3   = (const float*)d_in[8];
  const float* W4   = (const float*)d_in[9];
  const float* b4   = (const float*)d_in[10];
  const float* Wres = (const float*)d_in[11];
  const float* bres = (const float*)d_in[12];
  const float* Wop  = (const float*)d_in[13];
  const float* bop  = (const float*)d_in[14];
  float* out = (float*)d_out;

  const int N = in_sizes[0] / 128;
  const int E = in_sizes[1];
  const int nbuck = (N + 255) >> 8;

  char* p = (char*)d_ws;
  auto alloc = [&](size_t b) {
    char* r = p;
    p += (b + 255) & ~(size_t)255;
    return r;
  };
  int*            gcur_d  = (int*)alloc((size_t)nbuck * 4);
  int*            gcur_s  = (int*)alloc((size_t)nbuck * 4);
  unsigned*       dbuck   = (unsigned*)alloc((size_t)nbuck * BCAP * 4);
  unsigned char*  sbuck   = (unsigned char*)alloc((size_t)nbuck * BCAP);
  int*            col     = (int*)alloc((size_t)N * SLOTS * 4);
  int*            cnt_arr = (int*)alloc((size_t)N * 4);
  float*          snorm   = (float*)alloc((size_t)N * 4);
  float*          dnorm   = (float*)alloc((size_t)N * 4);
  unsigned short* Hbuf    = (unsigned short*)alloc((size_t)N * 64 * 2);
  unsigned short* Obuf    = (unsigned short*)alloc((size_t)N * 64 * 2);
  unsigned short* Rbuf    = (unsigned short*)alloc((size_t)N * 64 * 2);

  init_kernel<<<(nbuck + 255) / 256, 256, 0, stream>>>(gcur_d, gcur_s, nbuck);

  int ga = (E + ACHUNK - 1) / ACHUNK;
  bucket_kernel<<<ga, 256, 0, stream>>>(src, dst, gcur_d, gcur_s, dbuck, sbuck, E, nbuck);
  csr_kernel<<<nbuck, 256, 0, stream>>>(dbuck, gcur_d, col, cnt_arr, dnorm, N);
  degout_kernel<<<nbuck, 256, 0, stream>>>(sbuck, gcur_s, snorm, N);

  int gb = (N + 63) / 64;
  // Layer 1 (K=128, fp32 input) fused with residual GEMM
  gemm1_kernel<<<gb, 256, 0, stream>>>(x, W1, Wres, bres, snorm, Hbuf, Rbuf, N);
  agg_kernel<1><<<2048, 256, 0, stream>>>(Hbuf, cnt_arr, col, dnorm, b1, Obuf, N);
  // Layer 2
  gemm_bf16_kernel<<<gb, 256, 0, stream>>>(Obuf, W2, snorm, Hbuf, N);
  agg_kernel<1><<<2048, 256, 0, stream>>>(Hbuf, cnt_arr, col, dnorm, b2, Obuf, N);
  // Layer 3
  gemm_bf16_kernel<<<gb, 256, 0, stream>>>(Obuf, W3, snorm, Hbuf, N);
  agg_kernel<1><<<2048, 256, 0, stream>>>(Hbuf, cnt_arr, col, dnorm, b3, Obuf, N);
  // Layer 4 (no relu)
  gemm_bf16_kernel<<<gb, 256, 0, stream>>>(Obuf, W4, snorm, Hbuf, N);
  agg_kernel<0><<<2048, 256, 0, stream>>>(Hbuf, cnt_arr, col, dnorm, b4, Obuf, N);
  // Final: relu(O4 + R) @ Wop + bop
  final_kernel<<<gb, 256, 0, stream>>>(Obuf, Rbuf, Wop, bop, out, N);
}